// Round 10
// baseline (1819.225 us; speedup 1.0000x reference)
//
#include <hip/hip_runtime.h>
#include <hip/hip_cooperative_groups.h>
#include <hip/hip_bf16.h>
#include <math.h>

#define SS 160
#define DD 512
#define HH 8
#define MTOK 640
#define FFD 2048
#define NTT 257

#define EPI_RESID 1
#define EPI_GELU 2
#define EPI_QKV 3

typedef __attribute__((ext_vector_type(8))) short bfrag8;
typedef __attribute__((ext_vector_type(4))) float facc4;
typedef unsigned short u16;

#define SWZ(row, cb) ((cb) ^ (((row)&7) << 4))

namespace cg = cooperative_groups;

__device__ __forceinline__ void gload16(const void* g, void* l) {
  __builtin_amdgcn_global_load_lds(
      (const __attribute__((address_space(1))) void*)g,
      (__attribute__((address_space(3))) void*)l, 16, 0, 0);
}

__device__ __forceinline__ u16 f2b(float f) {
  __hip_bfloat16 hb = __float2bfloat16(f);
  return *reinterpret_cast<u16*>(&hb);
}

struct MegaArgs {
  const int *x, *stamp, *mask, *tm;
  const float *tok, *month, *day, *tiK, *tiV;
  const float *g0, *b0;
  const float *Wq, *bq, *Wk, *bk, *Wv, *bv, *Wo, *bo;
  const float *g1, *b1, *W1, *c1, *W2, *c2, *g2, *b2;
  float *out;
  float *h, *tb, *Skb, *Gb;
  __hip_bfloat16 *h_bf, *hh_bf, *fb_bf, *qkv_bf, *tikb, *wqkv, *wo_t, *w1_t, *w2_t;
};

// ================= prep (weights + tiK + embed/LN0) ========================
__device__ void wconv_body(const float* __restrict__ src,
                           __hip_bfloat16* __restrict__ dst,
                           int K, int N, int dls, int rowoff,
                           int l, int bx, int by, float (*tile)[65])
{
  src += (size_t)l * K * N;
  dst += (size_t)l * dls + (size_t)rowoff * K;
  int k0 = by * 64, n0 = bx * 64;
  int t = threadIdx.x;
  int r = t >> 2, c0 = (t & 3) * 16;
  #pragma unroll
  for (int j = 0; j < 16; j += 4) {
    float4 v4 = *(const float4*)&src[(size_t)(k0 + r) * N + n0 + c0 + j];
    tile[r][c0 + j + 0] = v4.x; tile[r][c0 + j + 1] = v4.y;
    tile[r][c0 + j + 2] = v4.z; tile[r][c0 + j + 3] = v4.w;
  }
  __syncthreads();
  union { u16 u[8]; uint4 v; } pk;
  #pragma unroll
  for (int half = 0; half < 2; ++half) {
    #pragma unroll
    for (int j = 0; j < 8; ++j)
      pk.u[j] = f2b(tile[c0 + half * 8 + j][r]);
    *(uint4*)&dst[(size_t)(n0 + r) * K + k0 + c0 + half * 8] = pk.v;
  }
}

__device__ void dev_prep(const MegaArgs& a, int idx, char* smem)
{
  float (*tile)[65] = (float (*)[65])smem;
  float* ssh = (float*)(smem + 16640);
  float* qsh = (float*)(smem + 16656);
  int tid = threadIdx.x;

  if (idx < 1536) {
    if (idx < 384) {
      int grp = idx / 128, r = idx % 128;
      int l = r / 64, t = r % 64;
      const float* src = grp == 0 ? a.Wq : (grp == 1 ? a.Wk : a.Wv);
      wconv_body(src, a.wqkv, 512, 512, 1536 * 512, 512 * grp, l, t % 8, t / 8, tile);
    } else if (idx < 512) {
      int r = idx - 384; int l = r / 64, t = r % 64;
      wconv_body(a.Wo, a.wo_t, 512, 512, 512 * 512, 0, l, t % 8, t / 8, tile);
    } else if (idx < 1024) {
      int r = idx - 512; int l = r / 256, t = r % 256;
      wconv_body(a.W1, a.w1_t, 512, 2048, 2048 * 512, 0, l, t % 32, t / 32, tile);
    } else {
      int r = idx - 1024; int l = r / 256, t = r % 256;
      wconv_body(a.W2, a.w2_t, 2048, 512, 512 * 2048, 0, l, t % 8, t / 8, tile);
    }
  } else if (idx < 1665) {
    int i = (idx - 1536) * 256 + tid;
    if (i < NTT * DD / 4) {
      float4 v = *(const float4*)(a.tiK + (size_t)i * 4);
      union { u16 u[4]; uint2 w; } pk;
      pk.u[0] = f2b(v.x); pk.u[1] = f2b(v.y);
      pk.u[2] = f2b(v.z); pk.u[3] = f2b(v.w);
      *(uint2*)(a.tikb + (size_t)i * 4) = pk.w;
    }
  } else {
    int m = idx - 1665;
    int b = m / SS, s = m % SS, t = tid;
    int tokid = a.x[m];
    float v0 = a.tok[tokid * DD + t];
    float v1 = a.tok[tokid * DD + t + 256];
    if (s > 0) {
      int sidx = (b * (SS - 1) + (s - 1)) * 3;
      int mo = a.stamp[sidx + 0], dy = a.stamp[sidx + 1];
      v0 += a.month[mo * DD + t]       + a.day[dy * DD + t];
      v1 += a.month[mo * DD + t + 256] + a.day[dy * DD + t + 256];
    }
    float sum = v0 + v1, sq = v0 * v0 + v1 * v1;
    #pragma unroll
    for (int off = 1; off < 64; off <<= 1) {
      sum += __shfl_xor(sum, off);
      sq  += __shfl_xor(sq , off);
    }
    if ((t & 63) == 0) { ssh[t >> 6] = sum; qsh[t >> 6] = sq; }
    __syncthreads();
    float fsum = ssh[0] + ssh[1] + ssh[2] + ssh[3];
    float fsq  = qsh[0] + qsh[1] + qsh[2] + qsh[3];
    float u = fsum * (1.0f / 512.0f);
    float var = fsq * (1.0f / 512.0f) - u * u;
    float r = rsqrtf(var + 1e-12f);
    float y0 = a.g0[t]       * ((v0 - u) * r) + a.b0[t];
    float y1 = a.g0[t + 256] * ((v1 - u) * r) + a.b0[t + 256];
    a.h[m * DD + t]        = y0;  a.h[m * DD + t + 256]  = y1;
    a.h_bf[m * DD + t]       = __float2bfloat16(y0);
    a.h_bf[m * DD + t + 256] = __float2bfloat16(y1);
  }
}

// ================= LayerNorm (one row) =====================================
__device__ void dev_ln(const float* __restrict__ in, const float* __restrict__ g,
                       const float* __restrict__ b, float* __restrict__ outf,
                       __hip_bfloat16* __restrict__ outb, int m, char* smem)
{
  float* ssh = (float*)smem;
  float* qsh = (float*)(smem + 16);
  int t = threadIdx.x;
  float v0 = in[m*DD + t];
  float v1 = in[m*DD + t + 256];
  float sum = v0+v1, sq = v0*v0+v1*v1;
  #pragma unroll
  for (int off=1; off<64; off<<=1) {
    sum += __shfl_xor(sum, off);
    sq  += __shfl_xor(sq , off);
  }
  if ((t&63)==0) { ssh[t>>6]=sum; qsh[t>>6]=sq; }
  __syncthreads();
  float fsum = ssh[0]+ssh[1]+ssh[2]+ssh[3];
  float fsq  = qsh[0]+qsh[1]+qsh[2]+qsh[3];
  float u = fsum * (1.0f/512.0f);
  float var = fsq * (1.0f/512.0f) - u*u;
  float r = rsqrtf(var + 1e-12f);
  float y0 = g[t]    *((v0-u)*r) + b[t];
  float y1 = g[t+256]*((v1-u)*r) + b[t+256];
  outf[m*DD+t]     = y0;
  outf[m*DD+t+256] = y1;
  if (outb) {
    outb[m*DD+t]     = __float2bfloat16(y0);
    outb[m*DD+t+256] = __float2bfloat16(y1);
  }
}

// ================= pipelined GEMM (KC=64 dbuf, 32 KB LDS) ==================
__device__ void dev_gemm(const __hip_bfloat16* __restrict__ A,
                         const __hip_bfloat16* __restrict__ Bt,
                         const float* __restrict__ bias,
                         const float* __restrict__ bias2,
                         const float* __restrict__ bias3,
                         const float* __restrict__ resid,
                         float* __restrict__ Cf,
                         __hip_bfloat16* __restrict__ Cb,
                         int N, int K, int epi, int v, int bxw, char* smem)
{
  const int tid = threadIdx.x, wv = tid >> 6, lane = tid & 63;
  const int bx = v % bxw, by = v / bxw;
  const int m0 = by * 64, n0 = bx * 64;
  const int wr = wv >> 1, wc = wv & 1;
  const int fr = lane & 15, fks = lane >> 4;
  char* As = smem;           // [2][8192]
  char* Bs = smem + 16384;   // [2][8192]
  const int NCH = K >> 6;
  const int offA = wv * 2048 + lane * 16;

  #define MSTAGE(c, buf) do {                                                 \
    _Pragma("unroll")                                                         \
    for (int i_ = 0; i_ < 2; ++i_) {                                          \
      int off = offA + i_ * 1024;                                             \
      int r_ = off >> 7, p_ = off & 127;                                      \
      int ps_ = p_ ^ ((r_ & 7) << 4);                                         \
      int ldso = (wv * 2048 + i_ * 1024) + (buf) * 8192;                      \
      gload16((const char*)A  + ((size_t)(m0 + r_) * K + (c) * 64) * 2 + ps_, \
              As + ldso);                                                     \
      gload16((const char*)Bt + ((size_t)(n0 + r_) * K + (c) * 64) * 2 + ps_, \
              Bs + ldso);                                                     \
    }                                                                         \
  } while (0)

  facc4 acc[2][2] = {};
  MSTAGE(0, 0);
  MSTAGE(1, 1);

  for (int c = 0; c < NCH; ++c) {
    if (c + 1 < NCH) asm volatile("s_waitcnt vmcnt(4)\n\ts_barrier" ::: "memory");
    else             asm volatile("s_waitcnt vmcnt(0)\n\ts_barrier" ::: "memory");
    const char* ab = As + (c & 1) * 8192;
    const char* bb = Bs + (c & 1) * 8192;
    bfrag8 af[2][2], bfv[2][2];
    #pragma unroll
    for (int ks = 0; ks < 2; ++ks) {
      #pragma unroll
      for (int mf = 0; mf < 2; ++mf) {
        int rA = wr * 32 + mf * 16 + fr;
        af[ks][mf] = *(const bfrag8*)(ab + rA * 128 + SWZ(rA, ks * 64 + fks * 16));
      }
      #pragma unroll
      for (int nf = 0; nf < 2; ++nf) {
        int rB = wc * 32 + nf * 16 + fr;
        bfv[ks][nf] = *(const bfrag8*)(bb + rB * 128 + SWZ(rB, ks * 64 + fks * 16));
      }
    }
    #pragma unroll
    for (int ks = 0; ks < 2; ++ks)
      #pragma unroll
      for (int mf = 0; mf < 2; ++mf)
        #pragma unroll
        for (int nf = 0; nf < 2; ++nf)
          acc[mf][nf] = __builtin_amdgcn_mfma_f32_16x16x32_bf16(
              af[ks][mf], bfv[ks][nf], acc[mf][nf], 0, 0, 0);
    asm volatile("s_barrier" ::: "memory");
    if (c + 2 < NCH) MSTAGE(c + 2, c & 1);
  }
  #undef MSTAGE

  #pragma unroll
  for (int mf = 0; mf < 2; ++mf) {
    #pragma unroll
    for (int nf = 0; nf < 2; ++nf) {
      int col = n0 + wc * 32 + nf * 16 + fr;
      float bb2;
      if (epi == EPI_QKV)
        bb2 = col < 512 ? bias[col] : (col < 1024 ? bias2[col - 512] : bias3[col - 1024]);
      else
        bb2 = bias[col];
      #pragma unroll
      for (int j = 0; j < 4; ++j) {
        int row = m0 + wr * 32 + mf * 16 + fks * 4 + j;
        float cvl = acc[mf][nf][j] + bb2;
        if (epi == EPI_RESID) {
          cvl += resid[(size_t)row * N + col];
          Cf[(size_t)row * N + col] = cvl;
        } else {
          if (epi == EPI_GELU) cvl = 0.5f * cvl * (1.0f + erff(cvl * 0.70710678118654752f));
          Cb[(size_t)row * N + col] = __float2bfloat16(cvl);
        }
      }
    }
  }
}

// ================= skg: Sk = QK^T, G = Q.tiK^T =============================
__device__ void dev_skg(const MegaArgs& a, int idx, char* smem)
{
  u16* As = (u16*)smem;          // 8192 B
  u16* Bs = (u16*)(smem + 8192); // 8192 B
  const __hip_bfloat16* qkv = a.qkv_bf;
  const int tid = threadIdx.x;
  const int wid = tid >> 6, lane = tid & 63;
  const int wr = wid >> 1, wc = wid & 1;
  const int fr = lane & 15, fks = lane >> 4;
  const int sr = tid >> 2, sc = (tid & 3) * 16;
  const int swz0 = sr * 128 + SWZ(sr, sc * 2);
  const int swz1 = sr * 128 + SWZ(sr, sc * 2 + 16);

  if (idx < 288) {
    const int z = idx / 9, rem = idx % 9;
    const int m0 = (rem / 3) * 64, n0 = (rem % 3) * 64;
    const int b = z >> 3, h = z & 7;
    const __hip_bfloat16* Aq = qkv + (size_t)b * SS * 1536 + h * 64;
    const __hip_bfloat16* Bt = qkv + (size_t)b * SS * 1536 + 512 + h * 64;
    float* C = a.Skb + (size_t)z * SS * SS;
    const int ar = min(m0 + sr, SS - 1), br = min(n0 + sr, SS - 1);
    uint4 av0 = *(const uint4*)(Aq + (size_t)ar * 1536 + sc);
    uint4 av1 = *(const uint4*)(Aq + (size_t)ar * 1536 + sc + 8);
    uint4 bv0 = *(const uint4*)(Bt + (size_t)br * 1536 + sc);
    uint4 bv1 = *(const uint4*)(Bt + (size_t)br * 1536 + sc + 8);
    *(uint4*)((char*)As + swz0) = av0;
    *(uint4*)((char*)As + swz1) = av1;
    *(uint4*)((char*)Bs + swz0) = bv0;
    *(uint4*)((char*)Bs + swz1) = bv1;
    __syncthreads();
    facc4 acc[2][2] = {};
    #pragma unroll
    for (int ks = 0; ks < 2; ++ks) {
      bfrag8 af[2], bfv[2];
      #pragma unroll
      for (int mf = 0; mf < 2; ++mf) {
        int rA = wr * 32 + mf * 16 + fr;
        af[mf] = *(const bfrag8*)((const char*)As + rA * 128 + SWZ(rA, 64 * ks + 16 * fks));
      }
      #pragma unroll
      for (int nf = 0; nf < 2; ++nf) {
        int rB = wc * 32 + nf * 16 + fr;
        bfv[nf] = *(const bfrag8*)((const char*)Bs + rB * 128 + SWZ(rB, 64 * ks + 16 * fks));
      }
      #pragma unroll
      for (int mf = 0; mf < 2; ++mf)
        #pragma unroll
        for (int nf = 0; nf < 2; ++nf)
          acc[mf][nf] = __builtin_amdgcn_mfma_f32_16x16x32_bf16(
              af[mf], bfv[nf], acc[mf][nf], 0, 0, 0);
    }
    #pragma unroll
    for (int mf = 0; mf < 2; ++mf)
      #pragma unroll
      for (int nf = 0; nf < 2; ++nf) {
        int col = n0 + wc * 32 + nf * 16 + fr;
        #pragma unroll
        for (int j = 0; j < 4; ++j) {
          int row = m0 + wr * 32 + mf * 16 + fks * 4 + j;
          if (row < SS && col < SS) C[row * SS + col] = acc[mf][nf][j];
        }
      }
  } else {
    int i2 = idx - 288;
    const int nb = i2 % 5, mb = (i2 / 5) % 10, h = i2 / 50;
    const int m0 = mb * 64, n0 = nb * 64;
    const __hip_bfloat16* Aq = qkv + h * 64;
    const __hip_bfloat16* Bt = a.tikb + h * 64;
    const int br = min(n0 + sr, NTT - 1);
    uint4 av0 = *(const uint4*)(Aq + (size_t)(m0 + sr) * 1536 + sc);
    uint4 av1 = *(const uint4*)(Aq + (size_t)(m0 + sr) * 1536 + sc + 8);
    uint4 bv0 = *(const uint4*)(Bt + (size_t)br * 512 + sc);
    uint4 bv1 = *(const uint4*)(Bt + (size_t)br * 512 + sc + 8);
    *(uint4*)((char*)As + swz0) = av0;
    *(uint4*)((char*)As + swz1) = av1;
    *(uint4*)((char*)Bs + swz0) = bv0;
    *(uint4*)((char*)Bs + swz1) = bv1;
    __syncthreads();
    facc4 acc[2][2] = {};
    #pragma unroll
    for (int ks = 0; ks < 2; ++ks) {
      bfrag8 af[2], bfv[2];
      #pragma unroll
      for (int mf = 0; mf < 2; ++mf) {
        int rA = wr * 32 + mf * 16 + fr;
        af[mf] = *(const bfrag8*)((const char*)As + rA * 128 + SWZ(rA, 64 * ks + 16 * fks));
      }
      #pragma unroll
      for (int nf = 0; nf < 2; ++nf) {
        int rB = wc * 32 + nf * 16 + fr;
        bfv[nf] = *(const bfrag8*)((const char*)Bs + rB * 128 + SWZ(rB, 64 * ks + 16 * fks));
      }
      #pragma unroll
      for (int mf = 0; mf < 2; ++mf)
        #pragma unroll
        for (int nf = 0; nf < 2; ++nf)
          acc[mf][nf] = __builtin_amdgcn_mfma_f32_16x16x32_bf16(
              af[mf], bfv[nf], acc[mf][nf], 0, 0, 0);
    }
    #pragma unroll
    for (int mf = 0; mf < 2; ++mf)
      #pragma unroll
      for (int nf = 0; nf < 2; ++nf) {
        int col = n0 + wc * 32 + nf * 16 + fr;
        #pragma unroll
        for (int j = 0; j < 4; ++j) {
          int row = m0 + wr * 32 + mf * 16 + fks * 4 + j;
          if (col < NTT)
            a.Gb[((size_t)h * MTOK + row) * NTT + col] = acc[mf][nf][j];
        }
      }
  }
}

// ================= attn: softmax + PV (wave-private rows, no barriers) =====
__device__ void dev_attn(const MegaArgs& a, int v, char* smem)
{
  const int ib = v % 20, h = (v / 20) % 8, b = v / 160;
  const int ib0 = ib * 8;
  const int tid = threadIdx.x, wv = tid >> 6, lane = tid & 63;
  float (*P)[176] = (float (*)[176])smem;                 // 5632 B
  int (*tmsh)[176] = (int (*)[176])(smem + 5632);         // 5632 B
  const __hip_bfloat16* qkv = a.qkv_bf;

  float rinvs[2];
  #pragma unroll
  for (int rr = 0; rr < 2; ++rr) {
    const int r = wv * 2 + rr, i = ib0 + r, m = b * SS + i;
    const float* Grow = a.Gb + ((size_t)h * MTOK + m) * NTT;
    const float* Srow = a.Skb + ((size_t)(b * 8 + h) * SS + i) * SS;
    const int* tmrow = a.tm + (size_t)m * SS;
    float sv[3];
    float mx = -1e30f;
    #pragma unroll
    for (int g = 0; g < 3; ++g) {
      int j = lane + g * 64;
      if (j < SS) {
        int t = tmrow[j];
        tmsh[r][j] = t;
        float s = (Srow[j] + Grow[t]) * 0.125f
                + 10000.0f * (1.0f - (float)a.mask[b * SS + j]);
        sv[g] = s; mx = fmaxf(mx, s);
      } else sv[g] = -1e30f;
    }
    #pragma unroll
    for (int off = 1; off < 64; off <<= 1) mx = fmaxf(mx, __shfl_xor(mx, off));
    float sum = 0.f;
    #pragma unroll
    for (int g = 0; g < 3; ++g) {
      int j = lane + g * 64;
      if (j < SS) { float p = expf(sv[g] - mx); P[r][j] = p; sum += p; }
    }
    #pragma unroll
    for (int off = 1; off < 64; off <<= 1) sum += __shfl_xor(sum, off);
    rinvs[rr] = 1.0f / sum;
  }

  const int r0 = wv * 2, r1 = r0 + 1;
  const int i0 = ib0 + r0, i1 = ib0 + r1;
  const __hip_bfloat16* vbase = qkv + (size_t)b * SS * 1536 + 1024 + h * 64 + lane;
  const float* tvbase = a.tiV + h * 64 + lane;
  float acc0 = 0.f, acc1 = 0.f;
  #pragma unroll 4
  for (int j = 0; j < SS; ++j) {
    float vv = __bfloat162float(vbase[(size_t)j * 1536]);
    float a0 = P[r0][j], a1 = P[r1][j];
    int t0 = tmsh[r0][j], t1 = tmsh[r1][j];
    acc0 += a0 * (vv + tvbase[(size_t)t0 * 512]);
    acc1 += a1 * (vv + tvbase[(size_t)t1 * 512]);
  }
  a.hh_bf[((size_t)(b * SS) + i0) * DD + h * 64 + lane] = __float2bfloat16(acc0 * rinvs[0]);
  a.hh_bf[((size_t)(b * SS) + i1) * DD + h * 64 + lane] = __float2bfloat16(acc1 * rinvs[1]);
}

// ================= the megakernel ==========================================
__global__ __launch_bounds__(256, 2) void mega(MegaArgs a)
{
  __shared__ alignas(16) char smem[32768];
  cg::grid_group grid = cg::this_grid();
  const int nb = gridDim.x, bid = blockIdx.x;

  for (int v = bid; v < 2305; v += nb) { dev_prep(a, v, smem); __syncthreads(); }
  __threadfence(); grid.sync();

  for (int l = 0; l < 2; ++l) {
    for (int v = bid; v < 240; v += nb)
      dev_gemm(a.h_bf, a.wqkv + (size_t)l * 1536 * 512,
               a.bq + l * DD, a.bk + l * DD, a.bv + l * DD,
               nullptr, nullptr, a.qkv_bf, 1536, 512, EPI_QKV, v, 24, smem);
    __threadfence(); grid.sync();

    for (int v = bid; v < 688; v += nb) { dev_skg(a, v, smem); __syncthreads(); }
    __threadfence(); grid.sync();

    for (int v = bid; v < 640; v += nb) dev_attn(a, v, smem);
    __threadfence(); grid.sync();

    for (int v = bid; v < 80; v += nb)
      dev_gemm(a.hh_bf, a.wo_t + (size_t)l * 512 * 512, a.bo + l * DD,
               nullptr, nullptr, a.h, a.tb, nullptr, 512, 512, EPI_RESID, v, 8, smem);
    __threadfence(); grid.sync();

    for (int v = bid; v < 640; v += nb) {
      dev_ln(a.tb, a.g1 + l * DD, a.b1 + l * DD, a.h, a.h_bf, v, smem);
      __syncthreads();
    }
    __threadfence(); grid.sync();

    for (int v = bid; v < 320; v += nb)
      dev_gemm(a.h_bf, a.w1_t + (size_t)l * 2048 * 512, a.c1 + l * FFD,
               nullptr, nullptr, nullptr, nullptr, a.fb_bf, 2048, 512, EPI_GELU, v, 32, smem);
    __threadfence(); grid.sync();

    for (int v = bid; v < 80; v += nb)
      dev_gemm(a.fb_bf, a.w2_t + (size_t)l * 512 * 2048, a.c2 + l * DD,
               nullptr, nullptr, a.h, a.tb, nullptr, 512, 2048, EPI_RESID, v, 8, smem);
    __threadfence(); grid.sync();

    for (int v = bid; v < 640; v += nb) {
      dev_ln(a.tb, a.g2 + l * DD, a.b2 + l * DD,
             (l == 1) ? a.out : a.h, (l == 1) ? nullptr : a.h_bf, v, smem);
      __syncthreads();
    }
    if (l == 0) { __threadfence(); grid.sync(); }
  }
}

// ================= fallback per-phase wrappers =============================
__global__ __launch_bounds__(256) void k_prep(MegaArgs a) {
  __shared__ alignas(16) char smem[32768];
  dev_prep(a, blockIdx.x, smem);
}
__global__ __launch_bounds__(256) void k_gemm(MegaArgs a,
    const __hip_bfloat16* A, const __hip_bfloat16* Bt,
    const float* bias, const float* bias2, const float* bias3,
    const float* resid, float* Cf, __hip_bfloat16* Cb,
    int N, int K, int epi, int bxw) {
  __shared__ alignas(16) char smem[32768];
  dev_gemm(A, Bt, bias, bias2, bias3, resid, Cf, Cb, N, K, epi, blockIdx.x, bxw, smem);
}
__global__ __launch_bounds__(256) void k_skg(MegaArgs a) {
  __shared__ alignas(16) char smem[32768];
  dev_skg(a, blockIdx.x, smem);
}
__global__ __launch_bounds__(256) void k_attn(MegaArgs a) {
  __shared__ alignas(16) char smem[32768];
  dev_attn(a, blockIdx.x, smem);
}
__global__ __launch_bounds__(256) void k_ln(MegaArgs a,
    const float* in, const float* g, const float* b,
    float* outf, __hip_bfloat16* outb) {
  __shared__ alignas(16) char smem[32768];
  dev_ln(in, g, b, outf, outb, blockIdx.x, smem);
}

// ================= launch ==================================================
extern "C" void kernel_launch(void* const* d_in, const int* in_sizes, int n_in,
                              void* d_out, int out_size, void* d_ws, size_t ws_size,
                              hipStream_t stream) {
  MegaArgs a;
  a.x     = (const int*)d_in[0];
  a.stamp = (const int*)d_in[1];
  a.mask  = (const int*)d_in[2];
  a.tm    = (const int*)d_in[3];
  a.tok   = (const float*)d_in[4];
  a.month = (const float*)d_in[5];
  a.day   = (const float*)d_in[6];
  a.tiK   = (const float*)d_in[7];
  a.tiV   = (const float*)d_in[8];
  a.g0    = (const float*)d_in[9];
  a.b0    = (const float*)d_in[10];
  a.Wq    = (const float*)d_in[11];
  a.bq    = (const float*)d_in[12];
  a.Wk    = (const float*)d_in[13];
  a.bk    = (const float*)d_in[14];
  a.Wv    = (const float*)d_in[15];
  a.bv    = (const float*)d_in[16];
  a.Wo    = (const float*)d_in[17];
  a.bo    = (const float*)d_in[18];
  a.g1    = (const float*)d_in[19];
  a.b1    = (const float*)d_in[20];
  a.W1    = (const float*)d_in[21];
  a.c1    = (const float*)d_in[22];
  a.W2    = (const float*)d_in[23];
  a.c2    = (const float*)d_in[24];
  a.g2    = (const float*)d_in[25];
  a.b2    = (const float*)d_in[26];
  a.out   = (float*)d_out;

  const size_t NT = (size_t)MTOK * DD;
  char* p = (char*)d_ws;
  a.h    = (float*)p;  p += NT * 4;
  a.tb   = (float*)p;  p += NT * 4;
  a.Skb  = (float*)p;  p += (size_t)32 * SS * SS * 4;
  a.Gb   = (float*)p;  p += (size_t)HH * MTOK * NTT * 4;
  a.h_bf   = (__hip_bfloat16*)p;  p += NT * 2;
  a.hh_bf  = (__hip_bfloat16*)p;  p += NT * 2;
  a.fb_bf  = (__hip_bfloat16*)p;  p += (size_t)MTOK * FFD * 2;
  a.qkv_bf = (__hip_bfloat16*)p;  p += (size_t)MTOK * 1536 * 2;
  a.tikb   = (__hip_bfloat16*)p;  p += (size_t)NTT * DD * 2;
  a.wqkv   = (__hip_bfloat16*)p;  p += (size_t)2 * 1536 * 512 * 2;
  a.wo_t   = (__hip_bfloat16*)p;  p += (size_t)2 * 512 * 512 * 2;
  a.w1_t   = (__hip_bfloat16*)p;  p += (size_t)2 * 2048 * 512 * 2;
  a.w2_t   = (__hip_bfloat16*)p;  p += (size_t)2 * 512 * 2048 * 2;

  void* params[] = { (void*)&a };
  hipError_t err = hipLaunchCooperativeKernel(
      (const void*)mega, dim3(512), dim3(256), params, 0, stream);

  if (err != hipSuccess) {
    // fallback: proven R5-style multi-dispatch sequence with same bodies
    k_prep<<<2305, 256, 0, stream>>>(a);
    for (int l = 0; l < 2; ++l) {
      k_gemm<<<240, 256, 0, stream>>>(a, a.h_bf, a.wqkv + (size_t)l * 1536 * 512,
          a.bq + l*DD, a.bk + l*DD, a.bv + l*DD,
          nullptr, nullptr, a.qkv_bf, 1536, 512, EPI_QKV, 24);
      k_skg<<<688, 256, 0, stream>>>(a);
      k_attn<<<640, 256, 0, stream>>>(a);
      k_gemm<<<80, 256, 0, stream>>>(a, a.hh_bf, a.wo_t + (size_t)l * 512 * 512,
          a.bo + l*DD, nullptr, nullptr, a.h, a.tb, nullptr, 512, 512, EPI_RESID, 8);
      k_ln<<<640, 256, 0, stream>>>(a, a.tb, a.g1 + l*DD, a.b1 + l*DD, a.h, a.h_bf);
      k_gemm<<<320, 256, 0, stream>>>(a, a.h_bf, a.w1_t + (size_t)l * 2048 * 512,
          a.c1 + l*FFD, nullptr, nullptr, nullptr, nullptr, a.fb_bf, 2048, 512, EPI_GELU, 32);
      k_gemm<<<80, 256, 0, stream>>>(a, a.fb_bf, a.w2_t + (size_t)l * 512 * 2048,
          a.c2 + l*DD, nullptr, nullptr, a.h, a.tb, nullptr, 512, 2048, EPI_RESID, 8);
      k_ln<<<640, 256, 0, stream>>>(a, a.tb, a.g2 + l*DD, a.b2 + l*DD,
          (l == 1) ? a.out : a.h, (l == 1) ? nullptr : a.h_bf);
    }
  }
}

// Round 12
// 146.319 us; speedup vs baseline: 12.4333x; 12.4333x over previous
//
#include <hip/hip_runtime.h>
#include <hip/hip_bf16.h>
#include <math.h>

#define SS 160
#define DD 512
#define HH 8
#define MTOK 640
#define FFD 2048
#define NTT 257   // T+1 time-embedding rows

typedef __attribute__((ext_vector_type(8))) short bfrag8;
typedef __attribute__((ext_vector_type(4))) float facc4;
typedef unsigned short u16;

#define SWZ(row, cb) ((cb) ^ (((row)&7) << 4))

__device__ __forceinline__ void gload16(const void* g, void* l) {
  __builtin_amdgcn_global_load_lds(
      (const __attribute__((address_space(1))) void*)g,
      (__attribute__((address_space(3))) void*)l, 16, 0, 0);
}

__device__ __forceinline__ u16 f2b(float f) {
  __hip_bfloat16 hb = __float2bfloat16(f);
  return *reinterpret_cast<u16*>(&hb);
}

// ================= prep_all ================================================
__device__ void wconv_body(const float* __restrict__ src,
                           __hip_bfloat16* __restrict__ dst,
                           int K, int N, int dls, int rowoff,
                           int l, int bx, int by, float (*tile)[65])
{
  src += (size_t)l * K * N;
  dst += (size_t)l * dls + (size_t)rowoff * K;
  int k0 = by * 64, n0 = bx * 64;
  int t = threadIdx.x;
  int r = t >> 2, c0 = (t & 3) * 16;
  #pragma unroll
  for (int j = 0; j < 16; j += 4) {
    float4 v4 = *(const float4*)&src[(size_t)(k0 + r) * N + n0 + c0 + j];
    tile[r][c0 + j + 0] = v4.x; tile[r][c0 + j + 1] = v4.y;
    tile[r][c0 + j + 2] = v4.z; tile[r][c0 + j + 3] = v4.w;
  }
  __syncthreads();
  union { u16 u[8]; uint4 v; } pk;
  #pragma unroll
  for (int half = 0; half < 2; ++half) {
    #pragma unroll
    for (int j = 0; j < 8; ++j)
      pk.u[j] = f2b(tile[c0 + half * 8 + j][r]);
    *(uint4*)&dst[(size_t)(n0 + r) * K + k0 + c0 + half * 8] = pk.v;
  }
}

__global__ __launch_bounds__(256) void prep_all(
    const float* __restrict__ Wq, const float* __restrict__ Wk,
    const float* __restrict__ Wv, const float* __restrict__ Wo,
    const float* __restrict__ W1, const float* __restrict__ W2,
    const float* __restrict__ tiK,
    __hip_bfloat16* __restrict__ wqkv, __hip_bfloat16* __restrict__ wo_t,
    __hip_bfloat16* __restrict__ w1_t, __hip_bfloat16* __restrict__ w2_t,
    __hip_bfloat16* __restrict__ tikb,
    const int* __restrict__ x, const int* __restrict__ stamp,
    const float* __restrict__ tok, const float* __restrict__ month,
    const float* __restrict__ day, const float* __restrict__ g0,
    const float* __restrict__ b0, float* __restrict__ h,
    __hip_bfloat16* __restrict__ hb)
{
  __shared__ float tile[64][65];
  __shared__ float ssh[4], qsh[4];
  int idx = blockIdx.x;
  int tid = threadIdx.x;

  if (idx < 1536) {
    if (idx < 384) {
      int grp = idx / 128, r = idx % 128;
      int l = r / 64, t = r % 64;
      const float* src = grp == 0 ? Wq : (grp == 1 ? Wk : Wv);
      wconv_body(src, wqkv, 512, 512, 1536 * 512, 512 * grp, l, t % 8, t / 8, tile);
    } else if (idx < 512) {
      int r = idx - 384; int l = r / 64, t = r % 64;
      wconv_body(Wo, wo_t, 512, 512, 512 * 512, 0, l, t % 8, t / 8, tile);
    } else if (idx < 1024) {
      int r = idx - 512; int l = r / 256, t = r % 256;
      wconv_body(W1, w1_t, 512, 2048, 2048 * 512, 0, l, t % 32, t / 32, tile);
    } else {
      int r = idx - 1024; int l = r / 256, t = r % 256;
      wconv_body(W2, w2_t, 2048, 512, 512 * 2048, 0, l, t % 8, t / 8, tile);
    }
  } else if (idx < 1665) {
    int i = (idx - 1536) * 256 + tid;
    if (i < NTT * DD / 4) {
      float4 v = *(const float4*)(tiK + (size_t)i * 4);
      union { u16 u[4]; uint2 w; } pk;
      pk.u[0] = f2b(v.x); pk.u[1] = f2b(v.y);
      pk.u[2] = f2b(v.z); pk.u[3] = f2b(v.w);
      *(uint2*)(tikb + (size_t)i * 4) = pk.w;
    }
  } else {
    int m = idx - 1665;
    int b = m / SS, s = m % SS, t = tid;
    int tokid = x[m];
    float v0 = tok[tokid * DD + t];
    float v1 = tok[tokid * DD + t + 256];
    if (s > 0) {
      int sidx = (b * (SS - 1) + (s - 1)) * 3;
      int mo = stamp[sidx + 0], dy = stamp[sidx + 1];
      v0 += month[mo * DD + t]       + day[dy * DD + t];
      v1 += month[mo * DD + t + 256] + day[dy * DD + t + 256];
    }
    float sum = v0 + v1, sq = v0 * v0 + v1 * v1;
    #pragma unroll
    for (int off = 1; off < 64; off <<= 1) {
      sum += __shfl_xor(sum, off);
      sq  += __shfl_xor(sq , off);
    }
    if ((t & 63) == 0) { ssh[t >> 6] = sum; qsh[t >> 6] = sq; }
    __syncthreads();
    float fsum = ssh[0] + ssh[1] + ssh[2] + ssh[3];
    float fsq  = qsh[0] + qsh[1] + qsh[2] + qsh[3];
    float u = fsum * (1.0f / 512.0f);
    float var = fsq * (1.0f / 512.0f) - u * u;
    float r = rsqrtf(var + 1e-12f);
    float y0 = g0[t]       * ((v0 - u) * r) + b0[t];
    float y1 = g0[t + 256] * ((v1 - u) * r) + b0[t + 256];
    h[m * DD + t]        = y0;  h[m * DD + t + 256]  = y1;
    hb[m * DD + t]       = __float2bfloat16(y0);
    hb[m * DD + t + 256] = __float2bfloat16(y1);
  }
}

// ---------------- LayerNorm ----------------
__global__ __launch_bounds__(256) void ln_kernel(
    const float* __restrict__ in, const float* __restrict__ g,
    const float* __restrict__ b, float* __restrict__ out,
    __hip_bfloat16* __restrict__ outb)
{
  int m = blockIdx.x; int t = threadIdx.x;
  float v0 = in[m*DD + t];
  float v1 = in[m*DD + t + 256];
  float sum = v0+v1, sq = v0*v0+v1*v1;
  #pragma unroll
  for (int off=1; off<64; off<<=1) {
    sum += __shfl_xor(sum, off);
    sq  += __shfl_xor(sq , off);
  }
  __shared__ float ssh[4], qsh[4];
  if ((t&63)==0) { ssh[t>>6]=sum; qsh[t>>6]=sq; }
  __syncthreads();
  float fsum = ssh[0]+ssh[1]+ssh[2]+ssh[3];
  float fsq  = qsh[0]+qsh[1]+qsh[2]+qsh[3];
  float u = fsum * (1.0f/512.0f);
  float var = fsq * (1.0f/512.0f) - u*u;
  float r = rsqrtf(var + 1e-12f);
  float y0 = g[t]    *((v0-u)*r) + b[t];
  float y1 = g[t+256]*((v1-u)*r) + b[t+256];
  out[m*DD+t]     = y0;
  out[m*DD+t+256] = y1;
  if (outb) {
    outb[m*DD+t]     = __float2bfloat16(y0);
    outb[m*DD+t+256] = __float2bfloat16(y1);
  }
}

// ========== pipelined MFMA GEMM (R5-proven, KC=128 dbuf) ==========
#define EPI_RESID 1
#define EPI_GELU 2
#define EPI_QKV 3

template<int EPI, int K>
__global__ __launch_bounds__(256) void gemm_ck(
    const __hip_bfloat16* __restrict__ A,
    const __hip_bfloat16* __restrict__ Bt,
    const float* __restrict__ bias,
    const float* __restrict__ bias2,
    const float* __restrict__ bias3,
    const float* __restrict__ resid,
    float* __restrict__ Cf,
    __hip_bfloat16* __restrict__ Cb,
    int N)
{
  constexpr int KC = 128;
  constexpr int NCH = K / KC;
  __shared__ u16 As[2][64 * KC];
  __shared__ u16 Bs[2][64 * KC];
  const int tid = threadIdx.x, wv = tid >> 6, lane = tid & 63;
  const int m0 = blockIdx.y * 64, n0 = blockIdx.x * 64;
  const int wr = wv >> 1, wc = wv & 1;
  const int fr = lane & 15, fks = lane >> 4;

  const int ldsq = (wv * 4) * 1024;
  const int off0 = ldsq + lane * 16;

  #define STAGE(c, buf) do {                                                  \
    _Pragma("unroll")                                                         \
    for (int i_ = 0; i_ < 4; ++i_) {                                          \
      int ldso = ldsq + i_ * 1024;                                            \
      int off = off0 + i_ * 1024;                                             \
      int r_ = off >> 8;                                                      \
      int p_ = off & 255;                                                     \
      int ps_ = p_ ^ ((r_ & 7) << 4);                                         \
      gload16((const char*)A  + ((size_t)(m0 + r_) * K + (c) * KC) * 2 + ps_, \
              (char*)&As[buf][0] + ldso);                                     \
      gload16((const char*)Bt + ((size_t)(n0 + r_) * K + (c) * KC) * 2 + ps_, \
              (char*)&Bs[buf][0] + ldso);                                     \
    }                                                                         \
  } while (0)

  facc4 acc[2][2] = {};
  STAGE(0, 0);
  STAGE(1, 1);

  #pragma unroll
  for (int c = 0; c < NCH; ++c) {
    if (c + 1 < NCH) asm volatile("s_waitcnt vmcnt(8)\n\ts_barrier" ::: "memory");
    else             asm volatile("s_waitcnt vmcnt(0)\n\ts_barrier" ::: "memory");
    const char* ab = (const char*)&As[c & 1][0];
    const char* bb = (const char*)&Bs[c & 1][0];
    #pragma unroll
    for (int ks = 0; ks < 4; ++ks) {
      bfrag8 af[2], bfv[2];
      #pragma unroll
      for (int mf = 0; mf < 2; ++mf) {
        int rA = wr * 32 + mf * 16 + fr;
        af[mf] = *(const bfrag8*)(ab + rA * 256 + SWZ(rA, ks * 64 + fks * 16));
      }
      #pragma unroll
      for (int nf = 0; nf < 2; ++nf) {
        int rB = wc * 32 + nf * 16 + fr;
        bfv[nf] = *(const bfrag8*)(bb + rB * 256 + SWZ(rB, ks * 64 + fks * 16));
      }
      #pragma unroll
      for (int mf = 0; mf < 2; ++mf)
        #pragma unroll
        for (int nf = 0; nf < 2; ++nf)
          acc[mf][nf] = __builtin_amdgcn_mfma_f32_16x16x32_bf16(
              af[mf], bfv[nf], acc[mf][nf], 0, 0, 0);
    }
    asm volatile("s_barrier" ::: "memory");
    if (c + 2 < NCH) STAGE(c + 2, c & 1);
  }
  #undef STAGE

  #pragma unroll
  for (int mf = 0; mf < 2; ++mf) {
    #pragma unroll
    for (int nf = 0; nf < 2; ++nf) {
      int col = n0 + wc * 32 + nf * 16 + fr;
      float bb;
      if (EPI == EPI_QKV)
        bb = col < 512 ? bias[col] : (col < 1024 ? bias2[col - 512] : bias3[col - 1024]);
      else
        bb = bias[col];
      #pragma unroll
      for (int j = 0; j < 4; ++j) {
        int row = m0 + wr * 32 + mf * 16 + fks * 4 + j;
        float c = acc[mf][nf][j] + bb;
        if (EPI == EPI_RESID) {
          c += resid[(size_t)row * N + col];
          Cf[(size_t)row * N + col] = c;
        } else {
          if (EPI == EPI_GELU) c = 0.5f * c * (1.0f + erff(c * 0.70710678118654752f));
          Cb[(size_t)row * N + col] = __float2bfloat16(c);
        }
      }
    }
  }
}

// ========== fused attention: scores (MFMA from L2) + softmax + PV ==========
__global__ __launch_bounds__(256) void attn_f(
    const __hip_bfloat16* __restrict__ qkv,
    const __hip_bfloat16* __restrict__ tikb,
    const int* __restrict__ tm, const int* __restrict__ mask,
    const float* __restrict__ tiV, __hip_bfloat16* __restrict__ hh)
{
  const int h = blockIdx.y, b = blockIdx.z;
  const int i0 = blockIdx.x * 8;
  const int tid = threadIdx.x, wv = tid >> 6, lane = tid & 63;
  const int fr = lane & 15, fks = lane >> 4;
  __shared__ float S[8][160];
  __shared__ float Gsh[8][272];
  __shared__ float P[8][176];
  __shared__ int tmsh[8][176];

  // ---- phase 1: S = q@k^T, G = q@tiK^T for this block's 8 rows ----
  bfrag8 aq0, aq1;
  {
    const __hip_bfloat16* qrow =
        qkv + (size_t)(b * SS + i0 + (fr < 8 ? fr : 7)) * 1536 + h * 64;
    aq0 = *(const bfrag8*)(qrow + fks * 8);
    aq1 = *(const bfrag8*)(qrow + 32 + fks * 8);
  }
  for (int tt = wv; tt < 27; tt += 4) {
    facc4 acc = {};
    if (tt < 10) {
      int j = tt * 16 + fr;   // < 160 always
      const __hip_bfloat16* krow = qkv + (size_t)(b * SS + j) * 1536 + 512 + h * 64;
      bfrag8 b0 = *(const bfrag8*)(krow + fks * 8);
      bfrag8 b1 = *(const bfrag8*)(krow + 32 + fks * 8);
      acc = __builtin_amdgcn_mfma_f32_16x16x32_bf16(aq0, b0, acc, 0, 0, 0);
      acc = __builtin_amdgcn_mfma_f32_16x16x32_bf16(aq1, b1, acc, 0, 0, 0);
      #pragma unroll
      for (int jj = 0; jj < 4; ++jj) {
        int qr = fks * 4 + jj;
        if (qr < 8) S[qr][tt * 16 + fr] = acc[jj];
      }
    } else {
      int t0 = (tt - 10) * 16;
      int t = min(t0 + fr, NTT - 1);   // clamp; cols >=257 never read
      const __hip_bfloat16* trow = tikb + (size_t)t * 512 + h * 64;
      bfrag8 b0 = *(const bfrag8*)(trow + fks * 8);
      bfrag8 b1 = *(const bfrag8*)(trow + 32 + fks * 8);
      acc = __builtin_amdgcn_mfma_f32_16x16x32_bf16(aq0, b0, acc, 0, 0, 0);
      acc = __builtin_amdgcn_mfma_f32_16x16x32_bf16(aq1, b1, acc, 0, 0, 0);
      #pragma unroll
      for (int jj = 0; jj < 4; ++jj) {
        int qr = fks * 4 + jj;
        if (qr < 8) Gsh[qr][t0 + fr] = acc[jj];
      }
    }
  }
  __syncthreads();

  // ---- phase 2: softmax (wave-private rows) ----
  float rinvs[2];
  #pragma unroll
  for (int rr = 0; rr < 2; ++rr) {
    const int r = wv * 2 + rr, i = i0 + r, m = b * SS + i;
    const int* tmrow = tm + (size_t)m * SS;
    float sv[3];
    float mx = -1e30f;
    #pragma unroll
    for (int g = 0; g < 3; ++g) {
      int j = lane + g * 64;
      if (j < SS) {
        int t = tmrow[j];
        tmsh[r][j] = t;
        float s = (S[r][j] + Gsh[r][t]) * 0.125f
                + 10000.0f * (1.0f - (float)mask[b * SS + j]);
        sv[g] = s; mx = fmaxf(mx, s);
      } else sv[g] = -1e30f;
    }
    #pragma unroll
    for (int off = 1; off < 64; off <<= 1) mx = fmaxf(mx, __shfl_xor(mx, off));
    float sum = 0.f;
    #pragma unroll
    for (int g = 0; g < 3; ++g) {
      int j = lane + g * 64;
      if (j < SS) { float p = expf(sv[g] - mx); P[r][j] = p; sum += p; }
    }
    #pragma unroll
    for (int off = 1; off < 64; off <<= 1) sum += __shfl_xor(sum, off);
    rinvs[rr] = 1.0f / sum;
  }

  // ---- PV (unchanged from attn2) ----
  const int r0 = wv * 2, r1 = r0 + 1;
  const int ii0 = i0 + r0, ii1 = i0 + r1;
  const __hip_bfloat16* vbase = qkv + (size_t)b * SS * 1536 + 1024 + h * 64 + lane;
  const float* tvbase = tiV + h * 64 + lane;
  float acc0 = 0.f, acc1 = 0.f;
  #pragma unroll 4
  for (int j = 0; j < SS; ++j) {
    float vv = __bfloat162float(vbase[(size_t)j * 1536]);
    float a0 = P[r0][j], a1 = P[r1][j];
    int t0 = tmsh[r0][j], t1 = tmsh[r1][j];
    acc0 += a0 * (vv + tvbase[(size_t)t0 * 512]);
    acc1 += a1 * (vv + tvbase[(size_t)t1 * 512]);
  }
  hh[((size_t)(b * SS) + ii0) * DD + h * 64 + lane] = __float2bfloat16(acc0 * rinvs[0]);
  hh[((size_t)(b * SS) + ii1) * DD + h * 64 + lane] = __float2bfloat16(acc1 * rinvs[1]);
}

// ---------------- launch ----------------
extern "C" void kernel_launch(void* const* d_in, const int* in_sizes, int n_in,
                              void* d_out, int out_size, void* d_ws, size_t ws_size,
                              hipStream_t stream) {
  const int*   x     = (const int*)d_in[0];
  const int*   stamp = (const int*)d_in[1];
  const int*   mask  = (const int*)d_in[2];
  const int*   tm    = (const int*)d_in[3];
  const float* tok   = (const float*)d_in[4];
  const float* month = (const float*)d_in[5];
  const float* day   = (const float*)d_in[6];
  const float* tiK   = (const float*)d_in[7];
  const float* tiV   = (const float*)d_in[8];
  const float* g0    = (const float*)d_in[9];
  const float* b0    = (const float*)d_in[10];
  const float* Wq    = (const float*)d_in[11];
  const float* bq    = (const float*)d_in[12];
  const float* Wk    = (const float*)d_in[13];
  const float* bk    = (const float*)d_in[14];
  const float* Wv    = (const float*)d_in[15];
  const float* bv    = (const float*)d_in[16];
  const float* Wo    = (const float*)d_in[17];
  const float* bo    = (const float*)d_in[18];
  const float* g1    = (const float*)d_in[19];
  const float* b1    = (const float*)d_in[20];
  const float* W1    = (const float*)d_in[21];
  const float* c1    = (const float*)d_in[22];
  const float* W2    = (const float*)d_in[23];
  const float* c2    = (const float*)d_in[24];
  const float* g2    = (const float*)d_in[25];
  const float* b2    = (const float*)d_in[26];

  float* out = (float*)d_out;
  const size_t NT = (size_t)MTOK * DD;

  char* p = (char*)d_ws;
  float* h    = (float*)p;  p += NT * 4;
  float* tb   = (float*)p;  p += NT * 4;
  __hip_bfloat16* h_bf   = (__hip_bfloat16*)p;  p += NT * 2;
  __hip_bfloat16* hh_bf  = (__hip_bfloat16*)p;  p += NT * 2;
  __hip_bfloat16* fb_bf  = (__hip_bfloat16*)p;  p += (size_t)MTOK * FFD * 2;
  __hip_bfloat16* qkv_bf = (__hip_bfloat16*)p;  p += (size_t)MTOK * 1536 * 2;
  __hip_bfloat16* tikb   = (__hip_bfloat16*)p;  p += (size_t)NTT * DD * 2;
  __hip_bfloat16* wqkv   = (__hip_bfloat16*)p;  p += (size_t)2 * 1536 * 512 * 2;
  __hip_bfloat16* wo_t   = (__hip_bfloat16*)p;  p += (size_t)2 * 512 * 512 * 2;
  __hip_bfloat16* w1_t   = (__hip_bfloat16*)p;  p += (size_t)2 * 2048 * 512 * 2;
  __hip_bfloat16* w2_t   = (__hip_bfloat16*)p;  p += (size_t)2 * 512 * 2048 * 2;

  prep_all<<<2305, 256, 0, stream>>>(Wq, Wk, Wv, Wo, W1, W2, tiK,
                                     wqkv, wo_t, w1_t, w2_t, tikb,
                                     x, stamp, tok, month, day, g0, b0, h, h_bf);

  // gemm_ck arg order: A, Bt, bias, bias2, bias3, resid, Cf, Cb, N  (9 args)
  for (int l = 0; l < 2; ++l) {
    gemm_ck<EPI_QKV, 512><<<dim3(24, 10), 256, 0, stream>>>(
        h_bf, wqkv + (size_t)l * 1536 * 512, bq + l*DD, bk + l*DD, bv + l*DD,
        nullptr, nullptr, qkv_bf, 1536);

    attn_f<<<dim3(20, 8, 4), 256, 0, stream>>>(qkv_bf, tikb, tm, mask, tiV, hh_bf);

    gemm_ck<EPI_RESID, 512><<<dim3(8, 10), 256, 0, stream>>>(
        hh_bf, wo_t + (size_t)l * 512 * 512, bo + l*DD, nullptr, nullptr,
        h, tb, nullptr, 512);
    ln_kernel<<<MTOK, 256, 0, stream>>>(tb, g1 + l*DD, b1 + l*DD, h, h_bf);

    gemm_ck<EPI_GELU, 512><<<dim3(32, 10), 256, 0, stream>>>(
        h_bf, w1_t + (size_t)l * 2048 * 512, c1 + l*FFD, nullptr, nullptr,
        nullptr, nullptr, fb_bf, 2048);

    gemm_ck<EPI_RESID, 2048><<<dim3(8, 10), 256, 0, stream>>>(
        fb_bf, w2_t + (size_t)l * 512 * 2048, c2 + l*DD, nullptr, nullptr,
        h, tb, nullptr, 512);
    ln_kernel<<<MTOK, 256, 0, stream>>>(tb, g2 + l*DD, b2 + l*DD,
                                        (l == 1) ? out : h,
                                        (l == 1) ? nullptr : h_bf);
  }
}